// Round 2
// baseline (535.747 us; speedup 1.0000x reference)
//
#include <hip/hip_runtime.h>
#include <hip/hip_bf16.h>

namespace {
constexpr int NPTS  = 65536;   // points per batch
constexpr int KNB   = 16;      // neighbors
constexpr int CMID  = 16;
constexpr int CIN   = 64;
constexpr int CADD  = 3;
constexpr int COUT  = 128;
constexpr int KREAL = 1072;    // 67*16
constexpr int KPAD  = 1088;    // 68*16 (c padded to 68)
constexpr int MT    = 32;      // points per block
constexpr int PSTR  = 1096;    // LDS row stride for pconv (+8 pad)
constexpr int WSTR  = 40;      // LDS row stride for W tile (32 + 8 pad)
constexpr int NKT   = KPAD / 32;  // 34 K-chunks in stage 2
}

typedef __attribute__((ext_vector_type(8))) __bf16 bf16x8;
typedef __attribute__((ext_vector_type(4))) float f32x4;

union ABFrag { bf16x8 v; uint4 u; };

__device__ __forceinline__ unsigned int pack_bf2(float a, float b) {
  __hip_bfloat162 h = __float22bfloat162_rn(make_float2(a, b));
  return *reinterpret_cast<unsigned int*>(&h);
}

// One-time: W [128][1072] f32 -> bf16 zero-padded to [128][1088] in workspace.
__global__ void convert_w(const float* __restrict__ W, unsigned short* __restrict__ Wb) {
  const int o = blockIdx.x;
  for (int k = threadIdx.x; k < KPAD; k += blockDim.x) {
    float v = (k < KREAL) ? W[o * KREAL + k] : 0.0f;
    __hip_bfloat16 h = __float2bfloat16(v);
    Wb[o * KPAD + k] = *reinterpret_cast<unsigned short*>(&h);
  }
}

__device__ __forceinline__ void load_w_chunk(const unsigned short* __restrict__ Wb,
                                             const float* __restrict__ W, int useWb,
                                             int o, int kb, uint4& v0, uint4& v1) {
  if (useWb) {
    const uint4* src = reinterpret_cast<const uint4*>(Wb + (size_t)o * KPAD + kb);
    v0 = src[0]; v1 = src[1];
  } else {
    if (kb < KREAL) {
      const float4* src = reinterpret_cast<const float4*>(W + (size_t)o * KREAL + kb);
      const float4 f0 = src[0], f1 = src[1], f2 = src[2], f3 = src[3];
      v0 = make_uint4(pack_bf2(f0.x, f0.y), pack_bf2(f0.z, f0.w),
                      pack_bf2(f1.x, f1.y), pack_bf2(f1.z, f1.w));
      v1 = make_uint4(pack_bf2(f2.x, f2.y), pack_bf2(f2.z, f2.w),
                      pack_bf2(f3.x, f3.y), pack_bf2(f3.z, f3.w));
    } else {
      v0 = make_uint4(0, 0, 0, 0);
      v1 = make_uint4(0, 0, 0, 0);
    }
  }
}

__global__ __launch_bounds__(256, 2) void pconv_fused(
    const float* __restrict__ feat,        // [2][65536][64]
    const int* __restrict__ nidx,          // [2][65536][16]
    const float* __restrict__ wn,          // [2][65536][16][16]
    const float* __restrict__ addf,        // [2][65536][16][3]
    const float* __restrict__ W,           // [128][1072]
    const float* __restrict__ bias,        // [128]
    const unsigned short* __restrict__ Wb, // [128][1088] bf16 (optional)
    int useWb,
    float* __restrict__ out)               // [2][65536][128]
{
  __shared__ __align__(16) unsigned short s_p[MT * PSTR];   // pconv tile, bf16 bits, k-order c*16+j
  __shared__ __align__(16) unsigned short s_w[COUT * WSTR]; // W k-slab, bf16 bits [o][k]

  const int tid  = threadIdx.x;
  const int wid  = tid >> 6;
  const int lane = tid & 63;
  const int q    = lane >> 4;   // quad
  const int l    = lane & 15;

  // W staging assignment (stage 2)
  const int o    = tid >> 1;    // output channel this thread stages
  const int half = tid & 1;     // which 16-element half of the 32-k slab

  // Prefetch first W chunk — overlaps the whole of stage 1.
  uint4 wv0, wv1;
  load_w_chunk(Wb, W, useWb, o, half * 16, wv0, wv1);

  // ---------------- stage 1: per-point MFMA pconv^T -> LDS ----------------
  // One wave per point; 16x16x32 MFMA with k zero-padded 16->32.
  // A = wn^T: A[m=j][k=nb]; B = gathered feat: B[k=nb][n=c]; D[m=j][n=c].
  {
    const int actk = (q < 2);   // quads 0,1 supply k=0..15; quads 2,3 supply zeros
    const f32x4 zacc = {0.f, 0.f, 0.f, 0.f};

#pragma unroll 2
    for (int pl = 0; pl < 8; ++pl) {
      const int p  = wid * 8 + pl;
      const int mg = blockIdx.x * MT + p;
      const int b  = mg >> 16;
      const float* fb = feat + (size_t)b * (NPTS * CIN);

      int nb[8] = {0, 0, 0, 0, 0, 0, 0, 0};
      if (actk) {
        const int4* ip = reinterpret_cast<const int4*>(nidx + (size_t)mg * KNB + q * 8);
        const int4 i0 = ip[0], i1 = ip[1];
        nb[0] = i0.x; nb[1] = i0.y; nb[2] = i0.z; nb[3] = i0.w;
        nb[4] = i1.x; nb[5] = i1.y; nb[6] = i1.z; nb[7] = i1.w;
      }

      // A-frag: element i <-> k=q*8+i; value wn[mg][k][j=l]
      ABFrag afr; afr.u = make_uint4(0, 0, 0, 0);
      if (actk) {
        const float* wp = wn + (size_t)mg * (KNB * CMID) + (q * 8) * CMID + l;
        float w0 = wp[0],       w1 = wp[CMID],     w2 = wp[2 * CMID], w3 = wp[3 * CMID];
        float w4 = wp[4 * CMID], w5 = wp[5 * CMID], w6 = wp[6 * CMID], w7 = wp[7 * CMID];
        afr.u = make_uint4(pack_bf2(w0, w1), pack_bf2(w2, w3),
                           pack_bf2(w4, w5), pack_bf2(w6, w7));
      }

      unsigned short* prow = s_p + p * PSTR;

      // 4 gathered-feat c-tiles
#pragma unroll
      for (int ct = 0; ct < 4; ++ct) {
        ABFrag bfr; bfr.u = make_uint4(0, 0, 0, 0);
        if (actk) {
          float f0 = fb[(size_t)nb[0] * CIN + ct * 16 + l];
          float f1 = fb[(size_t)nb[1] * CIN + ct * 16 + l];
          float f2 = fb[(size_t)nb[2] * CIN + ct * 16 + l];
          float f3 = fb[(size_t)nb[3] * CIN + ct * 16 + l];
          float f4 = fb[(size_t)nb[4] * CIN + ct * 16 + l];
          float f5 = fb[(size_t)nb[5] * CIN + ct * 16 + l];
          float f6 = fb[(size_t)nb[6] * CIN + ct * 16 + l];
          float f7 = fb[(size_t)nb[7] * CIN + ct * 16 + l];
          bfr.u = make_uint4(pack_bf2(f0, f1), pack_bf2(f2, f3),
                             pack_bf2(f4, f5), pack_bf2(f6, f7));
        }
        const f32x4 d = __builtin_amdgcn_mfma_f32_16x16x32_bf16(afr.v, bfr.v, zacc, 0, 0, 0);
        // D[row=j=q*4+r][col=c=ct*16+l] -> s_p[p][c*16+j]; contiguous in r.
        uint2 w2;
        w2.x = pack_bf2(d[0], d[1]);
        w2.y = pack_bf2(d[2], d[3]);
        *reinterpret_cast<uint2*>(prow + (ct * 16 + l) * 16 + q * 4) = w2;
      }

      // additional-features c-tile (c=64..67; col 3 = zero pad)
      {
        ABFrag bfa; bfa.u = make_uint4(0, 0, 0, 0);
        if (actk && l < CADD) {
          const float* ap = addf + (size_t)mg * (KNB * CADD) + (q * 8) * CADD + l;
          float a0 = ap[0],        a1 = ap[CADD],     a2 = ap[2 * CADD], a3 = ap[3 * CADD];
          float a4 = ap[4 * CADD], a5 = ap[5 * CADD], a6 = ap[6 * CADD], a7 = ap[7 * CADD];
          bfa.u = make_uint4(pack_bf2(a0, a1), pack_bf2(a2, a3),
                             pack_bf2(a4, a5), pack_bf2(a6, a7));
        }
        const f32x4 d = __builtin_amdgcn_mfma_f32_16x16x32_bf16(afr.v, bfa.v, zacc, 0, 0, 0);
        if (l < 4) {
          uint2 w2;
          w2.x = pack_bf2(d[0], d[1]);
          w2.y = pack_bf2(d[2], d[3]);
          *reinterpret_cast<uint2*>(prow + (64 + l) * 16 + q * 4) = w2;
        }
      }
    }
  }

  // ---------------- stage 2: out[32][128] = pconv[32][1088] @ Wb^T ----------------
  const int mtile = wid & 1;
  const int nbase = (wid >> 1) * 64;

  f32x4 acc2[4];
#pragma unroll
  for (int nt = 0; nt < 4; ++nt) acc2[nt] = (f32x4){0.f, 0.f, 0.f, 0.f};

  for (int kt = 0; kt < NKT; ++kt) {
    __syncthreads();  // iter 0: also covers stage-1 s_p writes
    {
      uint4* d = reinterpret_cast<uint4*>(s_w + o * WSTR + half * 16);
      d[0] = wv0; d[1] = wv1;
    }
    __syncthreads();
    if (kt + 1 < NKT) {  // prefetch next chunk; overlaps MFMA below
      load_w_chunk(Wb, W, useWb, o, (kt + 1) * 32 + half * 16, wv0, wv1);
    }

    const bf16x8 a = *reinterpret_cast<const bf16x8*>(
        s_p + (mtile * 16 + l) * PSTR + kt * 32 + q * 8);
#pragma unroll
    for (int nt = 0; nt < 4; ++nt) {
      const bf16x8 bb = *reinterpret_cast<const bf16x8*>(
          s_w + (nbase + nt * 16 + l) * WSTR + q * 8);
      acc2[nt] = __builtin_amdgcn_mfma_f32_16x16x32_bf16(a, bb, acc2[nt], 0, 0, 0);
    }
  }

  // epilogue: C/D layout col=lane&15, row=quad*4+reg
  const int mrow = blockIdx.x * MT + mtile * 16 + q * 4;
#pragma unroll
  for (int nt = 0; nt < 4; ++nt) {
    const int oc = nbase + nt * 16 + l;
    const float bv = bias[oc];
#pragma unroll
    for (int r = 0; r < 4; ++r) {
      out[(size_t)(mrow + r) * COUT + oc] = acc2[nt][r] + bv;
    }
  }
}

extern "C" void kernel_launch(void* const* d_in, const int* in_sizes, int n_in,
                              void* d_out, int out_size, void* d_ws, size_t ws_size,
                              hipStream_t stream) {
  const float* feat = (const float*)d_in[0];
  const int*   nidx = (const int*)d_in[1];
  const float* wn   = (const float*)d_in[2];
  const float* addf = (const float*)d_in[3];
  const float* W    = (const float*)d_in[4];
  const float* bias = (const float*)d_in[5];
  float* out = (float*)d_out;

  unsigned short* Wb = (unsigned short*)d_ws;
  const int useWb = (ws_size >= (size_t)COUT * KPAD * 2) ? 1 : 0;
  if (useWb) {
    convert_w<<<COUT, 256, 0, stream>>>(W, Wb);
  }
  const int nblocks = (2 * NPTS) / MT;  // 4096
  pconv_fused<<<nblocks, 256, 0, stream>>>(feat, nidx, wn, addf, W, bias, Wb, useWb, out);
}